// Round 1
// baseline (398.466 us; speedup 1.0000x reference)
//
#include <hip/hip_runtime.h>
#include <hip/hip_bf16.h>

// Problem: N=50000 nodes, E=300000 edges, C=128.
// out[i] = leaky( dinv[i]*(agg[src[i]] + xws[i]) + b_gcn ),
//   xw[e]  = [x[src]|x[dst]|ea[e]] @ (W_edge@W_gcn) + b_edge@W_gcn
//   dinv[i]= rsqrt(1 + indeg(src(i))),  xws = xw*dinv
//   agg[v] = sum_{dst(j)=v} xws[j]
// line_edge_index / batch inputs are not needed.

typedef __bf16 bf16x8 __attribute__((ext_vector_type(8)));
typedef float  f32x4  __attribute__((ext_vector_type(4)));

#define C_DIM 128

// ---------------- K0: W_comb = W_edge @ W_gcn (store transposed bf16), b_comb = b_edge @ W_gcn
__global__ void k_wcomb(const float* __restrict__ W_edge, const float* __restrict__ W_gcn,
                        const float* __restrict__ b_edge,
                        __bf16* __restrict__ W_T /*[128][384]*/, float* __restrict__ b_comb) {
    int idx = blockIdx.x * 256 + threadIdx.x;        // 384*128 outputs
    if (idx < 384 * 128) {
        int k = idx >> 7, c = idx & 127;
        float s = 0.f;
        for (int m = 0; m < 128; ++m) s += W_edge[k * 128 + m] * W_gcn[m * 128 + c];
        W_T[(size_t)c * 384 + k] = (__bf16)s;
    }
    if (blockIdx.x == 0 && threadIdx.x < 128) {
        int c = threadIdx.x;
        float s = 0.f;
        for (int m = 0; m < 128; ++m) s += b_edge[m] * W_gcn[m * 128 + c];
        b_comb[c] = s;
    }
}

// ---------------- K1: in-degree of original graph (over dst)
__global__ void k_indeg(const int* __restrict__ dst, int E, int* __restrict__ indeg) {
    int e = blockIdx.x * 256 + threadIdx.x;
    if (e < E) atomicAdd(&indeg[dst[e]], 1);
}

// ---------------- K2: exclusive scan of indeg -> ptr (and cursor copy). Single block, 1024 thr.
__global__ void k_scan(const int* __restrict__ indeg, int n,
                       int* __restrict__ ptr, int* __restrict__ cursor) {
    __shared__ int wsum[16];
    __shared__ int s_running;
    if (threadIdx.x == 0) s_running = 0;
    __syncthreads();
    const int lane = threadIdx.x & 63, wid = threadIdx.x >> 6;
    for (int base = 0; base < n; base += 1024) {
        int i = base + (int)threadIdx.x;
        int v = (i < n) ? indeg[i] : 0;
        // wave inclusive scan
        int incl = v;
        for (int off = 1; off < 64; off <<= 1) {
            int t = __shfl_up(incl, off);
            if (lane >= off) incl += t;
        }
        if (lane == 63) wsum[wid] = incl;
        __syncthreads();
        if (wid == 0 && lane < 16) {
            int s = wsum[lane];
            for (int off = 1; off < 16; off <<= 1) {
                int t = __shfl_up(s, off);
                if (lane >= off) s += t;
            }
            wsum[lane] = s;   // inclusive over wave sums
        }
        __syncthreads();
        int woff = wid ? wsum[wid - 1] : 0;
        int run = s_running;
        if (i < n) {
            int ex = run + woff + incl - v;
            ptr[i] = ex;
            cursor[i] = ex;
        }
        __syncthreads();
        if (threadIdx.x == 1023) s_running = run + wsum[15];
        __syncthreads();
    }
    if (threadIdx.x == 0) ptr[n] = s_running;
}

// ---------------- K3: place edge ids into CSR-by-dst
__global__ void k_place(const int* __restrict__ dst, int E,
                        int* __restrict__ cursor, int* __restrict__ adj) {
    int e = blockIdx.x * 256 + threadIdx.x;
    if (e < E) {
        int pos = atomicAdd(&cursor[dst[e]], 1);
        adj[pos] = e;
    }
}

// ---------------- K4: gathered GEMM  xws[e] = ([x[src]|x[dst]|ea] @ W_comb + b_comb) * dinv[e]
// Tile: 64 edges x 128 cols, 4 waves (2x2), mfma_f32_16x16x32_bf16, K=384 in 12 steps.
__global__ __launch_bounds__(256) void k_gemm(
    const float* __restrict__ x, const float* __restrict__ ea,
    const int* __restrict__ src, const int* __restrict__ dst,
    const __bf16* __restrict__ W_T, const float* __restrict__ b_comb,
    const int* __restrict__ indeg, float* __restrict__ xws, int E) {

    __shared__ __align__(16) __bf16 As[64][40];     // pad 32->40 (stride 80B) to break bank conflicts

    const int tid = threadIdx.x;
    const int ebase = blockIdx.x * 64;

    // staging role: row r (0..63), quarter q covers k = q*8..q*8+7 of the 32-wide K step
    const int r = tid >> 2, q = tid & 3;
    const int e_r = ebase + r;
    const int e_rc = (e_r < E) ? e_r : 0;
    const int s_r = src[e_rc], d_r = dst[e_rc];
    const float* pS = x  + (size_t)s_r  * C_DIM + q * 8;
    const float* pD = x  + (size_t)d_r  * C_DIM + q * 8;
    const float* pE = ea + (size_t)e_rc * C_DIM + q * 8;

    const int lane = tid & 63, wid = tid >> 6;
    const int wr = wid >> 1, wc = wid & 1;
    const int kc8 = (lane >> 4) * 8;              // k-chunk within 32-step (same perm for A and B)
    const int arow0 = wr * 32 + (lane & 15);
    const int bcol0 = wc * 64 + (lane & 15);

    f32x4 acc[2][4] = {};

    for (int g = 0; g < 3; ++g) {
        const float* rp = (g == 0) ? pS : ((g == 1) ? pD : pE);
#pragma unroll
        for (int s4 = 0; s4 < 4; ++s4) {
            const int kb = g * 128 + s4 * 32;
            const float* p = rp + s4 * 32;
            float4 f0 = *(const float4*)p;
            float4 f1 = *(const float4*)(p + 4);
            bf16x8 h;
            h[0] = (__bf16)f0.x; h[1] = (__bf16)f0.y; h[2] = (__bf16)f0.z; h[3] = (__bf16)f0.w;
            h[4] = (__bf16)f1.x; h[5] = (__bf16)f1.y; h[6] = (__bf16)f1.z; h[7] = (__bf16)f1.w;
            __syncthreads();                       // protect previous step's reads
            *(bf16x8*)&As[r][q * 8] = h;
            __syncthreads();

            bf16x8 a0 = *(const bf16x8*)&As[arow0][kc8];
            bf16x8 a1 = *(const bf16x8*)&As[arow0 + 16][kc8];
            const __bf16* wt = W_T + (size_t)kb + kc8;
#pragma unroll
            for (int n = 0; n < 4; ++n) {
                bf16x8 b = *(const bf16x8*)&wt[(size_t)(bcol0 + n * 16) * 384];
                acc[0][n] = __builtin_amdgcn_mfma_f32_16x16x32_bf16(a0, b, acc[0][n], 0, 0, 0);
                acc[1][n] = __builtin_amdgcn_mfma_f32_16x16x32_bf16(a1, b, acc[1][n], 0, 0, 0);
            }
        }
    }

    // epilogue: C/D layout col = lane&15, row = (lane>>4)*4 + j   [m89-verified]
#pragma unroll
    for (int m = 0; m < 2; ++m) {
#pragma unroll
        for (int j = 0; j < 4; ++j) {
            int row = wr * 32 + m * 16 + (lane >> 4) * 4 + j;
            int e = ebase + row;
            if (e < E) {
                float di = rsqrtf(1.0f + (float)indeg[src[e]]);
#pragma unroll
                for (int n = 0; n < 4; ++n) {
                    int c = wc * 64 + n * 16 + (lane & 15);
                    float v = acc[m][n][j] + b_comb[c];
                    xws[(size_t)e * C_DIM + c] = v * di;
                }
            }
        }
    }
}

// ---------------- K5: agg[v] = sum over incoming edges (CSR gather)
__global__ void k_agg(const float* __restrict__ xws, const int* __restrict__ ptr,
                      const int* __restrict__ adj, float* __restrict__ agg) {
    int v = blockIdx.x;
    int c = threadIdx.x;                // 128 threads
    int b0 = ptr[v], b1 = ptr[v + 1];
    float s = 0.f;
    for (int t = b0; t < b1; ++t) {
        int j = adj[t];
        s += xws[(size_t)j * C_DIM + c];
    }
    agg[(size_t)v * C_DIM + c] = s;
}

// ---------------- K6: out[i] = leaky( dinv[i]*(agg[src[i]] + xws[i]) + b_gcn )
__global__ void k_out(const float* __restrict__ xws, const float* __restrict__ agg,
                      const int* __restrict__ src, const int* __restrict__ indeg,
                      const float* __restrict__ b_gcn, float* __restrict__ out, int E) {
    int g = blockIdx.x * 256 + threadIdx.x;      // one float4 per thread
    if (g >= E * (C_DIM / 4)) return;
    int e = g >> 5, c4 = g & 31;
    int s = src[e];
    float di = rsqrtf(1.0f + (float)indeg[s]);
    float4 a = *(const float4*)&agg[(size_t)s * C_DIM + c4 * 4];
    float4 w = *(const float4*)&xws[(size_t)e * C_DIM + c4 * 4];
    float4 b = *(const float4*)&b_gcn[c4 * 4];
    float4 r;
    r.x = di * (a.x + w.x) + b.x;
    r.y = di * (a.y + w.y) + b.y;
    r.z = di * (a.z + w.z) + b.z;
    r.w = di * (a.w + w.w) + b.w;
    r.x = r.x > 0.f ? r.x : 0.01f * r.x;
    r.y = r.y > 0.f ? r.y : 0.01f * r.y;
    r.z = r.z > 0.f ? r.z : 0.01f * r.z;
    r.w = r.w > 0.f ? r.w : 0.01f * r.w;
    *(float4*)&out[(size_t)e * C_DIM + c4 * 4] = r;
}

extern "C" void kernel_launch(void* const* d_in, const int* in_sizes, int n_in,
                              void* d_out, int out_size, void* d_ws, size_t ws_size,
                              hipStream_t stream) {
    const float* x      = (const float*)d_in[0];
    const float* ea     = (const float*)d_in[1];
    const float* W_edge = (const float*)d_in[2];
    const float* b_edge = (const float*)d_in[3];
    const float* W_gcn  = (const float*)d_in[4];
    const float* b_gcn  = (const float*)d_in[5];
    const int*   ei     = (const int*)d_in[6];
    // d_in[7] = batch (unused), d_in[8] = line_edge_index (unused)

    const int C  = in_sizes[3];            // 128
    const int Nn = in_sizes[0] / C;        // 50000
    const int E  = in_sizes[1] / C;        // 300000
    const int* srcp = ei;
    const int* dstp = ei + E;

    char* ws = (char*)d_ws;
    size_t off = 0;
    auto alloc = [&](size_t bytes) { size_t o = off; off = (off + bytes + 255) & ~(size_t)255; return o; };
    __bf16* W_T    = (__bf16*)(ws + alloc((size_t)384 * 128 * sizeof(__bf16)));
    float*  b_comb = (float*)(ws + alloc(128 * sizeof(float)));
    int*    indeg  = (int*)(ws + alloc((size_t)Nn * sizeof(int)));
    int*    ptr    = (int*)(ws + alloc((size_t)(Nn + 1) * sizeof(int)));
    int*    cursor = (int*)(ws + alloc((size_t)Nn * sizeof(int)));
    int*    adj    = (int*)(ws + alloc((size_t)E * sizeof(int)));
    float*  xws    = (float*)(ws + alloc((size_t)E * C * sizeof(float)));
    float*  agg    = (float*)(ws + alloc((size_t)Nn * C * sizeof(float)));
    // total ~181 MB of workspace

    hipMemsetAsync(indeg, 0, (size_t)Nn * sizeof(int), stream);
    k_wcomb<<<192, 256, 0, stream>>>(W_edge, W_gcn, b_edge, W_T, b_comb);
    k_indeg<<<(E + 255) / 256, 256, 0, stream>>>(dstp, E, indeg);
    k_scan<<<1, 1024, 0, stream>>>(indeg, Nn, ptr, cursor);
    k_place<<<(E + 255) / 256, 256, 0, stream>>>(dstp, E, cursor, adj);
    k_gemm<<<(E + 63) / 64, 256, 0, stream>>>(x, ea, srcp, dstp, W_T, b_comb, indeg, xws, E);
    k_agg<<<Nn, 128, 0, stream>>>(xws, ptr, adj, agg);
    k_out<<<(E * (C / 4) + 255) / 256, 256, 0, stream>>>(xws, agg, srcp, indeg, b_gcn, (float*)d_out, E);
}

// Round 2
// 353.958 us; speedup vs baseline: 1.1257x; 1.1257x over previous
//
#include <hip/hip_runtime.h>
#include <hip/hip_bf16.h>

// Problem: N=50000 nodes, E=300000 edges, C=128.
// out[i] = leaky( dinv[i]*(agg[src[i]] + xws[i]) + b_gcn ),
//   xw[e]  = [x[src]|x[dst]|ea[e]] @ (W_edge@W_gcn) + b_edge@W_gcn
//   dinv[i]= rsqrt(1 + indeg(src(i))),  xws = xw*dinv   (stored bf16)
//   agg[v] = sum_{dst(j)=v} xws[j]
// line_edge_index / batch inputs are not needed.

typedef __bf16 bf16x8 __attribute__((ext_vector_type(8)));
typedef float  f32x4  __attribute__((ext_vector_type(4)));

#define C_DIM 128

__device__ __forceinline__ float bfu_lo(unsigned u) { return __uint_as_float(u << 16); }
__device__ __forceinline__ float bfu_hi(unsigned u) { return __uint_as_float(u & 0xffff0000u); }

// ---------------- K0: W_comb = W_edge @ W_gcn (store transposed bf16), b_comb = b_edge @ W_gcn
__global__ void k_wcomb(const float* __restrict__ W_edge, const float* __restrict__ W_gcn,
                        const float* __restrict__ b_edge,
                        __bf16* __restrict__ W_T /*[128][384]*/, float* __restrict__ b_comb) {
    int idx = blockIdx.x * 256 + threadIdx.x;        // 384*128 outputs
    if (idx < 384 * 128) {
        int k = idx >> 7, c = idx & 127;
        float s = 0.f;
        for (int m = 0; m < 128; ++m) s += W_edge[k * 128 + m] * W_gcn[m * 128 + c];
        W_T[(size_t)c * 384 + k] = (__bf16)s;
    }
    if (blockIdx.x == 0 && threadIdx.x < 128) {
        int c = threadIdx.x;
        float s = 0.f;
        for (int m = 0; m < 128; ++m) s += b_edge[m] * W_gcn[m * 128 + c];
        b_comb[c] = s;
    }
}

// ---------------- K1: in-degree of original graph (over dst)
__global__ void k_indeg(const int* __restrict__ dst, int E, int* __restrict__ indeg) {
    int e = blockIdx.x * 256 + threadIdx.x;
    if (e < E) atomicAdd(&indeg[dst[e]], 1);
}

// ---------------- K2: exclusive scan of indeg -> ptr (and cursor copy). Single block, 1024 thr.
__global__ void k_scan(const int* __restrict__ indeg, int n,
                       int* __restrict__ ptr, int* __restrict__ cursor) {
    __shared__ int wsum[16];
    __shared__ int s_running;
    if (threadIdx.x == 0) s_running = 0;
    __syncthreads();
    const int lane = threadIdx.x & 63, wid = threadIdx.x >> 6;
    for (int base = 0; base < n; base += 1024) {
        int i = base + (int)threadIdx.x;
        int v = (i < n) ? indeg[i] : 0;
        int incl = v;
        for (int off = 1; off < 64; off <<= 1) {
            int t = __shfl_up(incl, off);
            if (lane >= off) incl += t;
        }
        if (lane == 63) wsum[wid] = incl;
        __syncthreads();
        if (wid == 0 && lane < 16) {
            int s = wsum[lane];
            for (int off = 1; off < 16; off <<= 1) {
                int t = __shfl_up(s, off);
                if (lane >= off) s += t;
            }
            wsum[lane] = s;
        }
        __syncthreads();
        int woff = wid ? wsum[wid - 1] : 0;
        int run = s_running;
        if (i < n) {
            int ex = run + woff + incl - v;
            ptr[i] = ex;
            cursor[i] = ex;
        }
        __syncthreads();
        if (threadIdx.x == 1023) s_running = run + wsum[15];
        __syncthreads();
    }
    if (threadIdx.x == 0) ptr[n] = s_running;
}

// ---------------- K3: place edge ids into CSR-by-dst
__global__ void k_place(const int* __restrict__ dst, int E,
                        int* __restrict__ cursor, int* __restrict__ adj) {
    int e = blockIdx.x * 256 + threadIdx.x;
    if (e < E) {
        int pos = atomicAdd(&cursor[dst[e]], 1);
        adj[pos] = e;
    }
}

// ---------------- K4: gathered GEMM  xws[e] = ([x[src]|x[dst]|ea] @ W_comb + b_comb) * dinv[e]
// Tile: 64 edges x 128 cols, 4 waves (2x2), mfma_f32_16x16x32_bf16.
// Whole 64x384 A-tile staged ONCE (XOR-swizzled 16B units), then 12 unrolled
// K-steps with zero barriers. Epilogue repacks via LDS for bf16x8 stores.
__global__ __launch_bounds__(256) void k_gemm(
    const float* __restrict__ x, const float* __restrict__ ea,
    const int* __restrict__ src, const int* __restrict__ dst,
    const __bf16* __restrict__ W_T, const float* __restrict__ b_comb,
    const int* __restrict__ indeg, __bf16* __restrict__ xws, int E) {

    __shared__ __align__(16) __bf16 As[64 * 384];   // 48KB, swizzled: unit16 = col8 ^ (row&7)

    const int tid = threadIdx.x;
    const int ebase = blockIdx.x * 64;

    // staging role: row r (0..63), quarter q covers floats q*8..q*8+7 of each 32-chunk
    const int r = tid >> 2, q = tid & 3;
    const int e_r = ebase + r;
    const int e_rc = (e_r < E) ? e_r : 0;
    const int s_r = src[e_rc], d_r = dst[e_rc];
    const float* rows0 = x  + (size_t)s_r  * C_DIM;
    const float* rows1 = x  + (size_t)d_r  * C_DIM;
    const float* rows2 = ea + (size_t)e_rc * C_DIM;

#pragma unroll
    for (int g = 0; g < 3; ++g) {
        const float* rp = (g == 0) ? rows0 : ((g == 1) ? rows1 : rows2);
#pragma unroll
        for (int s4 = 0; s4 < 4; ++s4) {
            const float* p = rp + s4 * 32 + q * 8;
            float4 f0 = *(const float4*)p;
            float4 f1 = *(const float4*)(p + 4);
            bf16x8 h;
            h[0] = (__bf16)f0.x; h[1] = (__bf16)f0.y; h[2] = (__bf16)f0.z; h[3] = (__bf16)f0.w;
            h[4] = (__bf16)f1.x; h[5] = (__bf16)f1.y; h[6] = (__bf16)f1.z; h[7] = (__bf16)f1.w;
            int col8 = g * 16 + s4 * 4 + q;                  // 16B unit index within row
            *(bf16x8*)&As[r * 384 + ((col8 ^ (r & 7)) << 3)] = h;
        }
    }
    __syncthreads();

    const int lane = tid & 63, wid = tid >> 6;
    const int wr = wid >> 1, wc = wid & 1;
    const int kc8 = (lane >> 4);                  // 16B unit within 32-wide K step (0..3)
    const int arow0 = wr * 32 + (lane & 15);
    const int arow1 = arow0 + 16;
    const int bcol0 = wc * 64 + (lane & 15);

    f32x4 acc[2][4] = {};

#pragma unroll
    for (int ks = 0; ks < 12; ++ks) {             // kb = ks*32
        int col8 = ks * 4 + kc8;
        bf16x8 a0 = *(const bf16x8*)&As[arow0 * 384 + ((col8 ^ (arow0 & 7)) << 3)];
        bf16x8 a1 = *(const bf16x8*)&As[arow1 * 384 + ((col8 ^ (arow1 & 7)) << 3)];
        const __bf16* wt = W_T + ks * 32 + kc8 * 8;
#pragma unroll
        for (int n = 0; n < 4; ++n) {
            bf16x8 b = *(const bf16x8*)&wt[(size_t)(bcol0 + n * 16) * 384];
            acc[0][n] = __builtin_amdgcn_mfma_f32_16x16x32_bf16(a0, b, acc[0][n], 0, 0, 0);
            acc[1][n] = __builtin_amdgcn_mfma_f32_16x16x32_bf16(a1, b, acc[1][n], 0, 0, 0);
        }
    }

    // epilogue: acc -> LDS (bf16, final values) -> coalesced bf16x8 stores
    __syncthreads();
#pragma unroll
    for (int m = 0; m < 2; ++m) {
#pragma unroll
        for (int j = 0; j < 4; ++j) {
            int row = wr * 32 + m * 16 + (lane >> 4) * 4 + j;
            int e = ebase + row;
            float di = 0.f;
            if (e < E) di = rsqrtf(1.0f + (float)indeg[src[e]]);
#pragma unroll
            for (int n = 0; n < 4; ++n) {
                int c = wc * 64 + n * 16 + (lane & 15);
                As[row * 136 + c] = (__bf16)((acc[m][n][j] + b_comb[c]) * di);
            }
        }
    }
    __syncthreads();
    if (e_r < E) {
        __bf16* outp = xws + (size_t)e_r * C_DIM + q * 32;
#pragma unroll
        for (int i = 0; i < 4; ++i) {
            bf16x8 vv = *(const bf16x8*)&As[r * 136 + q * 32 + i * 8];
            *(bf16x8*)(outp + i * 8) = vv;
        }
    }
}

// ---------------- K5: agg[v] = sum over incoming edges (CSR gather, bf16 in, f32 out)
__global__ void k_agg(const __bf16* __restrict__ xws, const int* __restrict__ ptr,
                      const int* __restrict__ adj, float* __restrict__ agg) {
    int v = blockIdx.x;
    int c = threadIdx.x;                // 64 threads, cols 2c / 2c+1
    int b0 = ptr[v], b1 = ptr[v + 1];
    float s0 = 0.f, s1 = 0.f;
    for (int t = b0; t < b1; ++t) {
        int j = adj[t];
        unsigned u = *(const unsigned*)(xws + (size_t)j * C_DIM + c * 2);
        s0 += bfu_lo(u);
        s1 += bfu_hi(u);
    }
    float2 o = make_float2(s0, s1);
    *(float2*)&agg[(size_t)v * C_DIM + c * 2] = o;
}

// ---------------- K6: out[i] = leaky( dinv[i]*(agg[src[i]] + xws[i]) + b_gcn )
__global__ void k_out(const __bf16* __restrict__ xws, const float* __restrict__ agg,
                      const int* __restrict__ src, const int* __restrict__ indeg,
                      const float* __restrict__ b_gcn, float* __restrict__ out, int E) {
    int g = blockIdx.x * 256 + threadIdx.x;      // one float4-of-output per thread
    if (g >= E * (C_DIM / 4)) return;
    int e = g >> 5, c4 = (g & 31) * 4;
    int s = src[e];
    float di = rsqrtf(1.0f + (float)indeg[s]);
    uint2 u = *(const uint2*)(xws + (size_t)e * C_DIM + c4);
    float4 a = *(const float4*)&agg[(size_t)s * C_DIM + c4];
    float4 b = *(const float4*)&b_gcn[c4];
    float4 r;
    r.x = di * (a.x + bfu_lo(u.x)) + b.x;
    r.y = di * (a.y + bfu_hi(u.x)) + b.y;
    r.z = di * (a.z + bfu_lo(u.y)) + b.z;
    r.w = di * (a.w + bfu_hi(u.y)) + b.w;
    r.x = r.x > 0.f ? r.x : 0.01f * r.x;
    r.y = r.y > 0.f ? r.y : 0.01f * r.y;
    r.z = r.z > 0.f ? r.z : 0.01f * r.z;
    r.w = r.w > 0.f ? r.w : 0.01f * r.w;
    *(float4*)&out[(size_t)e * C_DIM + c4] = r;
}

extern "C" void kernel_launch(void* const* d_in, const int* in_sizes, int n_in,
                              void* d_out, int out_size, void* d_ws, size_t ws_size,
                              hipStream_t stream) {
    const float* x      = (const float*)d_in[0];
    const float* ea     = (const float*)d_in[1];
    const float* W_edge = (const float*)d_in[2];
    const float* b_edge = (const float*)d_in[3];
    const float* W_gcn  = (const float*)d_in[4];
    const float* b_gcn  = (const float*)d_in[5];
    const int*   ei     = (const int*)d_in[6];
    // d_in[7] = batch (unused), d_in[8] = line_edge_index (unused)

    const int C  = in_sizes[3];            // 128
    const int Nn = in_sizes[0] / C;        // 50000
    const int E  = in_sizes[1] / C;        // 300000
    const int* srcp = ei;
    const int* dstp = ei + E;

    char* ws = (char*)d_ws;
    size_t off = 0;
    auto alloc = [&](size_t bytes) { size_t o = off; off = (off + bytes + 255) & ~(size_t)255; return o; };
    __bf16* W_T    = (__bf16*)(ws + alloc((size_t)384 * 128 * sizeof(__bf16)));
    float*  b_comb = (float*)(ws + alloc(128 * sizeof(float)));
    int*    indeg  = (int*)(ws + alloc((size_t)Nn * sizeof(int)));
    int*    ptr    = (int*)(ws + alloc((size_t)(Nn + 1) * sizeof(int)));
    int*    cursor = (int*)(ws + alloc((size_t)Nn * sizeof(int)));
    int*    adj    = (int*)(ws + alloc((size_t)E * sizeof(int)));
    __bf16* xws    = (__bf16*)(ws + alloc((size_t)E * C * sizeof(__bf16)));
    float*  agg    = (float*)(ws + alloc((size_t)Nn * C * sizeof(float)));

    hipMemsetAsync(indeg, 0, (size_t)Nn * sizeof(int), stream);
    k_wcomb<<<192, 256, 0, stream>>>(W_edge, W_gcn, b_edge, W_T, b_comb);
    k_indeg<<<(E + 255) / 256, 256, 0, stream>>>(dstp, E, indeg);
    k_scan<<<1, 1024, 0, stream>>>(indeg, Nn, ptr, cursor);
    k_place<<<(E + 255) / 256, 256, 0, stream>>>(dstp, E, cursor, adj);
    k_gemm<<<(E + 63) / 64, 256, 0, stream>>>(x, ea, srcp, dstp, W_T, b_comb, indeg, xws, E);
    k_agg<<<Nn, 64, 0, stream>>>(xws, ptr, adj, agg);
    k_out<<<(E * (C / 4) + 255) / 256, 256, 0, stream>>>(xws, agg, srcp, indeg, b_gcn, (float*)d_out, E);
}

// Round 4
// 297.180 us; speedup vs baseline: 1.3408x; 1.1911x over previous
//
#include <hip/hip_runtime.h>
#include <hip/hip_bf16.h>

// Problem: N=50000 nodes, E=300000 edges, C=128.
// out[i] = leaky( dinv[i]*(agg[src[i]] + xws[i]) + b_gcn ),
//   xw[e]  = [x[src]|x[dst]|ea[e]] @ (W_edge@W_gcn) + b_edge@W_gcn
//   dinv[i]= rsqrt(1 + indeg(src(i))),  xws = xw*dinv   (stored bf16)
//   agg[v] = sum_{dst(j)=v} xws[j]                      (stored bf16)
// line_edge_index / batch inputs are not needed.

typedef __bf16 bf16x8 __attribute__((ext_vector_type(8)));
typedef float  f32x4  __attribute__((ext_vector_type(4)));

#define C_DIM 128

__device__ __forceinline__ float bfu_lo(unsigned u) { return __uint_as_float(u << 16); }
__device__ __forceinline__ float bfu_hi(unsigned u) { return __uint_as_float(u & 0xffff0000u); }
__device__ __forceinline__ unsigned bf16_bits(float f) {
    __bf16 h = (__bf16)f;
    return (unsigned)__builtin_bit_cast(unsigned short, h);
}

// ---------------- K0: W_comb = W_edge @ W_gcn stored in MFMA B-fragment order, b_comb = b_edge @ W_gcn
// Fragment layout: for frag (ks 0..11, col16 0..7), lane l (=kc8*16 + c15) holds
// W_comb[ks*32 + kc8*8 + j][col16*16 + c15], j=0..7, at Wf[((ks*8+col16)*64 + l)*8 + j].
// A wave's B-frag load is then 64 contiguous 16B chunks = one coalesced 1KB transaction.
__global__ void k_wcomb(const float* __restrict__ W_edge, const float* __restrict__ W_gcn,
                        const float* __restrict__ b_edge,
                        __bf16* __restrict__ Wf, float* __restrict__ b_comb) {
    int idx = blockIdx.x * 256 + threadIdx.x;        // 384*128 outputs
    if (idx < 384 * 128) {
        int k = idx >> 7, c = idx & 127;
        float s = 0.f;
        for (int m = 0; m < 128; ++m) s += W_edge[k * 128 + m] * W_gcn[m * 128 + c];
        int ks = k >> 5, kc8 = (k >> 3) & 3, j = k & 7;
        int col16 = c >> 4, c15 = c & 15;
        Wf[(size_t)(((ks * 8 + col16) * 64) + kc8 * 16 + c15) * 8 + j] = (__bf16)s;
    }
    if (blockIdx.x == 0 && threadIdx.x < 128) {
        int c = threadIdx.x;
        float s = 0.f;
        for (int m = 0; m < 128; ++m) s += b_edge[m] * W_gcn[m * 128 + c];
        b_comb[c] = s;
    }
}

// ---------------- K1: in-degree of original graph (over dst)
__global__ void k_indeg(const int* __restrict__ dst, int E, int* __restrict__ indeg) {
    int e = blockIdx.x * 256 + threadIdx.x;
    if (e < E) atomicAdd(&indeg[dst[e]], 1);
}

// ---------------- K2: exclusive scan of indeg -> ptr (and cursor copy). Single block, 1024 thr.
__global__ void k_scan(const int* __restrict__ indeg, int n,
                       int* __restrict__ ptr, int* __restrict__ cursor) {
    __shared__ int wsum[16];
    __shared__ int s_running;
    if (threadIdx.x == 0) s_running = 0;
    __syncthreads();
    const int lane = threadIdx.x & 63, wid = threadIdx.x >> 6;
    for (int base = 0; base < n; base += 1024) {
        int i = base + (int)threadIdx.x;
        int v = (i < n) ? indeg[i] : 0;
        int incl = v;
        for (int off = 1; off < 64; off <<= 1) {
            int t = __shfl_up(incl, off);
            if (lane >= off) incl += t;
        }
        if (lane == 63) wsum[wid] = incl;
        __syncthreads();
        if (wid == 0 && lane < 16) {
            int s = wsum[lane];
            for (int off = 1; off < 16; off <<= 1) {
                int t = __shfl_up(s, off);
                if (lane >= off) s += t;
            }
            wsum[lane] = s;
        }
        __syncthreads();
        int woff = wid ? wsum[wid - 1] : 0;
        int run = s_running;
        if (i < n) {
            int ex = run + woff + incl - v;
            ptr[i] = ex;
            cursor[i] = ex;
        }
        __syncthreads();
        if (threadIdx.x == 1023) s_running = run + wsum[15];
        __syncthreads();
    }
    if (threadIdx.x == 0) ptr[n] = s_running;
}

// ---------------- K3: place edge ids into CSR-by-dst
__global__ void k_place(const int* __restrict__ dst, int E,
                        int* __restrict__ cursor, int* __restrict__ adj) {
    int e = blockIdx.x * 256 + threadIdx.x;
    if (e < E) {
        int pos = atomicAdd(&cursor[dst[e]], 1);
        adj[pos] = e;
    }
}

// ---------------- K4: gathered GEMM  xws[e] = ([x[src]|x[dst]|ea] @ W_comb + b_comb) * dinv[e]
// Tile: 64 edges x 128 cols, 4 waves (2x2), mfma_f32_16x16x32_bf16.
// A-tile staged once in LDS (XOR-swizzled); B read coalesced from fragment-ordered Wf.
__global__ __launch_bounds__(256) void k_gemm(
    const float* __restrict__ x, const float* __restrict__ ea,
    const int* __restrict__ src, const int* __restrict__ dst,
    const __bf16* __restrict__ Wf, const float* __restrict__ b_comb,
    const int* __restrict__ indeg, __bf16* __restrict__ xws, int E) {

    __shared__ __align__(16) __bf16 As[64 * 384];   // 48KB, swizzled: unit16 = col8 ^ (row&7)

    const int tid = threadIdx.x;
    const int ebase = blockIdx.x * 64;

    // staging role: row r (0..63), quarter q covers floats q*8..q*8+7 of each 32-chunk
    const int r = tid >> 2, q = tid & 3;
    const int e_r = ebase + r;
    const int e_rc = (e_r < E) ? e_r : 0;
    const int s_r = src[e_rc], d_r = dst[e_rc];
    const float* rows0 = x  + (size_t)s_r  * C_DIM;
    const float* rows1 = x  + (size_t)d_r  * C_DIM;
    const float* rows2 = ea + (size_t)e_rc * C_DIM;

#pragma unroll
    for (int g = 0; g < 3; ++g) {
        const float* rp = (g == 0) ? rows0 : ((g == 1) ? rows1 : rows2);
#pragma unroll
        for (int s4 = 0; s4 < 4; ++s4) {
            const float* p = rp + s4 * 32 + q * 8;
            float4 f0 = *(const float4*)p;
            float4 f1 = *(const float4*)(p + 4);
            bf16x8 h;
            h[0] = (__bf16)f0.x; h[1] = (__bf16)f0.y; h[2] = (__bf16)f0.z; h[3] = (__bf16)f0.w;
            h[4] = (__bf16)f1.x; h[5] = (__bf16)f1.y; h[6] = (__bf16)f1.z; h[7] = (__bf16)f1.w;
            int col8 = g * 16 + s4 * 4 + q;                  // 16B unit index within row
            *(bf16x8*)&As[r * 384 + ((col8 ^ (r & 7)) << 3)] = h;
        }
    }
    __syncthreads();

    const int lane = tid & 63, wid = tid >> 6;
    const int wr = wid >> 1, wc = wid & 1;
    const int kc8 = (lane >> 4);                  // 16B unit within 32-wide K step (0..3)
    const int arow0 = wr * 32 + (lane & 15);
    const int arow1 = arow0 + 16;

    // coalesced B: frag (ks, wc*4+n) at Wf + ((ks*8 + wc*4 + n)*64 + lane)*8
    const __bf16* wfb = Wf + ((size_t)(wc * 4) * 64 + lane) * 8;

    f32x4 acc[2][4] = {};

#pragma unroll
    for (int ks = 0; ks < 12; ++ks) {             // kb = ks*32
        int col8 = ks * 4 + kc8;
        bf16x8 a0 = *(const bf16x8*)&As[arow0 * 384 + ((col8 ^ (arow0 & 7)) << 3)];
        bf16x8 a1 = *(const bf16x8*)&As[arow1 * 384 + ((col8 ^ (arow1 & 7)) << 3)];
#pragma unroll
        for (int n = 0; n < 4; ++n) {
            bf16x8 b = *(const bf16x8*)&wfb[(size_t)(ks * 8 + n) * 64 * 8];
            acc[0][n] = __builtin_amdgcn_mfma_f32_16x16x32_bf16(a0, b, acc[0][n], 0, 0, 0);
            acc[1][n] = __builtin_amdgcn_mfma_f32_16x16x32_bf16(a1, b, acc[1][n], 0, 0, 0);
        }
    }

    // epilogue: acc -> LDS (bf16, final values) -> coalesced bf16x8 stores
    __syncthreads();
#pragma unroll
    for (int m = 0; m < 2; ++m) {
#pragma unroll
        for (int j = 0; j < 4; ++j) {
            int row = wr * 32 + m * 16 + (lane >> 4) * 4 + j;
            int e = ebase + row;
            float di = 0.f;
            if (e < E) di = rsqrtf(1.0f + (float)indeg[src[e]]);
#pragma unroll
            for (int n = 0; n < 4; ++n) {
                int c = wc * 64 + n * 16 + (lane & 15);
                As[row * 136 + c] = (__bf16)((acc[m][n][j] + b_comb[c]) * di);
            }
        }
    }
    __syncthreads();
    if (e_r < E) {
        __bf16* outp = xws + (size_t)e_r * C_DIM + q * 32;
#pragma unroll
        for (int i = 0; i < 4; ++i) {
            bf16x8 vv = *(const bf16x8*)&As[r * 136 + q * 32 + i * 8];
            *(bf16x8*)(outp + i * 8) = vv;
        }
    }
}

// ---------------- K5: agg[v] = sum over incoming edges (CSR gather, bf16 in, bf16 out)
__global__ void k_agg(const __bf16* __restrict__ xws, const int* __restrict__ ptr,
                      const int* __restrict__ adj, __bf16* __restrict__ agg) {
    int v = blockIdx.x;
    int c = threadIdx.x;                // 64 threads, cols 2c / 2c+1
    int b0 = ptr[v], b1 = ptr[v + 1];
    float s0 = 0.f, s1 = 0.f;
    for (int t = b0; t < b1; ++t) {
        int j = adj[t];
        unsigned u = *(const unsigned*)(xws + (size_t)j * C_DIM + c * 2);
        s0 += bfu_lo(u);
        s1 += bfu_hi(u);
    }
    unsigned o = bf16_bits(s0) | (bf16_bits(s1) << 16);
    *(unsigned*)(agg + (size_t)v * C_DIM + c * 2) = o;
}

// ---------------- K6: out[i] = leaky( dinv[i]*(agg[src[i]] + xws[i]) + b_gcn )
__global__ void k_out(const __bf16* __restrict__ xws, const __bf16* __restrict__ agg,
                      const int* __restrict__ src, const int* __restrict__ indeg,
                      const float* __restrict__ b_gcn, float* __restrict__ out, int E) {
    int g = blockIdx.x * 256 + threadIdx.x;      // one float4-of-output per thread
    if (g >= E * (C_DIM / 4)) return;
    int e = g >> 5, c4 = (g & 31) * 4;
    int s = src[e];
    float di = rsqrtf(1.0f + (float)indeg[s]);
    uint2 u = *(const uint2*)(xws + (size_t)e * C_DIM + c4);
    uint2 au = *(const uint2*)(agg + (size_t)s * C_DIM + c4);
    float4 b = *(const float4*)&b_gcn[c4];
    float4 r;
    r.x = di * (bfu_lo(au.x) + bfu_lo(u.x)) + b.x;
    r.y = di * (bfu_hi(au.x) + bfu_hi(u.x)) + b.y;
    r.z = di * (bfu_lo(au.y) + bfu_lo(u.y)) + b.z;
    r.w = di * (bfu_hi(au.y) + bfu_hi(u.y)) + b.w;
    r.x = r.x > 0.f ? r.x : 0.01f * r.x;
    r.y = r.y > 0.f ? r.y : 0.01f * r.y;
    r.z = r.z > 0.f ? r.z : 0.01f * r.z;
    r.w = r.w > 0.f ? r.w : 0.01f * r.w;
    *(float4*)&out[(size_t)e * C_DIM + c4] = r;
}

extern "C" void kernel_launch(void* const* d_in, const int* in_sizes, int n_in,
                              void* d_out, int out_size, void* d_ws, size_t ws_size,
                              hipStream_t stream) {
    const float* x      = (const float*)d_in[0];
    const float* ea     = (const float*)d_in[1];
    const float* W_edge = (const float*)d_in[2];
    const float* b_edge = (const float*)d_in[3];
    const float* W_gcn  = (const float*)d_in[4];
    const float* b_gcn  = (const float*)d_in[5];
    const int*   ei     = (const int*)d_in[6];
    // d_in[7] = batch (unused), d_in[8] = line_edge_index (unused)

    const int C  = in_sizes[3];            // 128
    const int Nn = in_sizes[0] / C;        // 50000
    const int E  = in_sizes[1] / C;        // 300000
    const int* srcp = ei;
    const int* dstp = ei + E;

    char* ws = (char*)d_ws;
    size_t off = 0;
    auto alloc = [&](size_t bytes) { size_t o = off; off = (off + bytes + 255) & ~(size_t)255; return o; };
    __bf16* Wf     = (__bf16*)(ws + alloc((size_t)384 * 128 * sizeof(__bf16)));
    float*  b_comb = (float*)(ws + alloc(128 * sizeof(float)));
    int*    indeg  = (int*)(ws + alloc((size_t)Nn * sizeof(int)));
    int*    ptr    = (int*)(ws + alloc((size_t)(Nn + 1) * sizeof(int)));
    int*    cursor = (int*)(ws + alloc((size_t)Nn * sizeof(int)));
    int*    adj    = (int*)(ws + alloc((size_t)E * sizeof(int)));
    __bf16* xws    = (__bf16*)(ws + alloc((size_t)E * C * sizeof(__bf16)));
    __bf16* agg    = (__bf16*)(ws + alloc((size_t)Nn * C * sizeof(__bf16)));

    (void)hipMemsetAsync(indeg, 0, (size_t)Nn * sizeof(int), stream);
    k_wcomb<<<192, 256, 0, stream>>>(W_edge, W_gcn, b_edge, Wf, b_comb);
    k_indeg<<<(E + 255) / 256, 256, 0, stream>>>(dstp, E, indeg);
    k_scan<<<1, 1024, 0, stream>>>(indeg, Nn, ptr, cursor);
    k_place<<<(E + 255) / 256, 256, 0, stream>>>(dstp, E, cursor, adj);
    k_gemm<<<(E + 63) / 64, 256, 0, stream>>>(x, ea, srcp, dstp, Wf, b_comb, indeg, xws, E);
    k_agg<<<Nn, 64, 0, stream>>>(xws, ptr, adj, agg);
    k_out<<<(E * (C / 4) + 255) / 256, 256, 0, stream>>>(xws, agg, srcp, indeg, b_gcn, (float*)d_out, E);
}

// Round 5
// 291.226 us; speedup vs baseline: 1.3682x; 1.0204x over previous
//
#include <hip/hip_runtime.h>
#include <hip/hip_bf16.h>

// Problem: N=50000 nodes, E=300000 edges, C=128.
// Factored: W_comb = W_edge@W_gcn = [W1;W2;W3] (3 x 128x128 blocks).
//   P1 = x@W1, P2 = x@W2            (dense stream GEMMs, bf16)
//   xws[e] = (ea[e]@W3 + P1[src]+P2[dst] + b_comb) * dinv[e]   (bf16)
//   dinv[e] = rsqrt(1 + indeg(src(e)))
//   agg[v]  = sum_{dst(j)=v} xws[j]  (bf16)
//   out[e]  = leaky( dinv[e]*(agg[src[e]] + xws[e]) + b_gcn )
// line_edge_index / batch inputs are not needed.

typedef __bf16 bf16x8 __attribute__((ext_vector_type(8)));
typedef float  f32x4  __attribute__((ext_vector_type(4)));

#define C_DIM 128

__device__ __forceinline__ float bfu_lo(unsigned u) { return __uint_as_float(u << 16); }
__device__ __forceinline__ float bfu_hi(unsigned u) { return __uint_as_float(u & 0xffff0000u); }
__device__ __forceinline__ unsigned bf16_bits(float f) {
    __bf16 h = (__bf16)f;
    return (unsigned)__builtin_bit_cast(unsigned short, h);
}

// ---------------- K0: W_comb in MFMA B-fragment order (12 ks x 8 col16 frags), b_comb
// Frag (ksAbs, col16): lane l (=kc8*16+c15) holds W_comb[ksAbs*32+kc8*8+j][col16*16+c15]
// at Wf[((ksAbs*8+col16)*64 + l)*8 + j]  -> wave B-load = 1KB fully coalesced.
__global__ void k_wcomb(const float* __restrict__ W_edge, const float* __restrict__ W_gcn,
                        const float* __restrict__ b_edge,
                        __bf16* __restrict__ Wf, float* __restrict__ b_comb) {
    int idx = blockIdx.x * 256 + threadIdx.x;        // 384*128 outputs
    if (idx < 384 * 128) {
        int k = idx >> 7, c = idx & 127;
        float s = 0.f;
        for (int m = 0; m < 128; ++m) s += W_edge[k * 128 + m] * W_gcn[m * 128 + c];
        int ks = k >> 5, kc8 = (k >> 3) & 3, j = k & 7;
        int col16 = c >> 4, c15 = c & 15;
        Wf[(size_t)(((ks * 8 + col16) * 64) + kc8 * 16 + c15) * 8 + j] = (__bf16)s;
    }
    if (blockIdx.x == 0 && threadIdx.x < 128) {
        int c = threadIdx.x;
        float s = 0.f;
        for (int m = 0; m < 128; ++m) s += b_edge[m] * W_gcn[m * 128 + c];
        b_comb[c] = s;
    }
}

// ---------------- K1: in-degree (over dst)
__global__ void k_indeg(const int* __restrict__ dst, int E, int* __restrict__ indeg) {
    int e = blockIdx.x * 256 + threadIdx.x;
    if (e < E) atomicAdd(&indeg[dst[e]], 1);
}

// ---------------- K2: exclusive scan of indeg -> ptr, cursor
__global__ void k_scan(const int* __restrict__ indeg, int n,
                       int* __restrict__ ptr, int* __restrict__ cursor) {
    __shared__ int wsum[16];
    __shared__ int s_running;
    if (threadIdx.x == 0) s_running = 0;
    __syncthreads();
    const int lane = threadIdx.x & 63, wid = threadIdx.x >> 6;
    for (int base = 0; base < n; base += 1024) {
        int i = base + (int)threadIdx.x;
        int v = (i < n) ? indeg[i] : 0;
        int incl = v;
        for (int off = 1; off < 64; off <<= 1) {
            int t = __shfl_up(incl, off);
            if (lane >= off) incl += t;
        }
        if (lane == 63) wsum[wid] = incl;
        __syncthreads();
        if (wid == 0 && lane < 16) {
            int s = wsum[lane];
            for (int off = 1; off < 16; off <<= 1) {
                int t = __shfl_up(s, off);
                if (lane >= off) s += t;
            }
            wsum[lane] = s;
        }
        __syncthreads();
        int woff = wid ? wsum[wid - 1] : 0;
        int run = s_running;
        if (i < n) {
            int ex = run + woff + incl - v;
            ptr[i] = ex;
            cursor[i] = ex;
        }
        __syncthreads();
        if (threadIdx.x == 1023) s_running = run + wsum[15];
        __syncthreads();
    }
    if (threadIdx.x == 0) ptr[n] = s_running;
}

// ---------------- K3: place edge ids into CSR-by-dst
__global__ void k_place(const int* __restrict__ dst, int E,
                        int* __restrict__ cursor, int* __restrict__ adj) {
    int e = blockIdx.x * 256 + threadIdx.x;
    if (e < E) {
        int pos = atomicAdd(&cursor[dst[e]], 1);
        adj[pos] = e;
    }
}

// ---------------- K4a: P1 = x@W1, P2 = x@W2 (dense, A streamed; shared A-stage)
__global__ __launch_bounds__(256) void k_p12(
    const float* __restrict__ x, const __bf16* __restrict__ Wf,
    __bf16* __restrict__ P1, __bf16* __restrict__ P2, int M) {

    __shared__ __align__(16) __bf16 As[64 * 136];

    const int tid = threadIdx.x;
    const int mbase = blockIdx.x * 64;
    const int r = tid >> 2, q = tid & 3;
    const int m_r = mbase + r;
    const int m_rc = (m_r < M) ? m_r : 0;
    const float* rp = x + (size_t)m_rc * C_DIM;

#pragma unroll
    for (int s4 = 0; s4 < 4; ++s4) {
        const float* p = rp + s4 * 32 + q * 8;
        float4 f0 = *(const float4*)p;
        float4 f1 = *(const float4*)(p + 4);
        bf16x8 h;
        h[0] = (__bf16)f0.x; h[1] = (__bf16)f0.y; h[2] = (__bf16)f0.z; h[3] = (__bf16)f0.w;
        h[4] = (__bf16)f1.x; h[5] = (__bf16)f1.y; h[6] = (__bf16)f1.z; h[7] = (__bf16)f1.w;
        int u = s4 * 4 + q;                              // 16B unit 0..15
        *(bf16x8*)&As[r * 128 + ((u ^ (r & 7)) << 3)] = h;
    }
    __syncthreads();

    const int lane = tid & 63, wid = tid >> 6;
    const int wr = wid >> 1, wc = wid & 1;
    const int kc8 = lane >> 4;
    const int arow0 = wr * 32 + (lane & 15);
    const int arow1 = arow0 + 16;
    const __bf16* wfb = Wf + ((size_t)(wc * 4) * 64 + lane) * 8;

    f32x4 acc1[2][4] = {};
    f32x4 acc2[2][4] = {};

#pragma unroll
    for (int ks = 0; ks < 4; ++ks) {
        int u = ks * 4 + kc8;
        bf16x8 a0 = *(const bf16x8*)&As[arow0 * 128 + ((u ^ (arow0 & 7)) << 3)];
        bf16x8 a1 = *(const bf16x8*)&As[arow1 * 128 + ((u ^ (arow1 & 7)) << 3)];
#pragma unroll
        for (int n = 0; n < 4; ++n) {
            bf16x8 b1 = *(const bf16x8*)&wfb[(size_t)(ks * 8 + n) * 64 * 8];
            bf16x8 b2 = *(const bf16x8*)&wfb[(size_t)((ks + 4) * 8 + n) * 64 * 8];
            acc1[0][n] = __builtin_amdgcn_mfma_f32_16x16x32_bf16(a0, b1, acc1[0][n], 0, 0, 0);
            acc1[1][n] = __builtin_amdgcn_mfma_f32_16x16x32_bf16(a1, b1, acc1[1][n], 0, 0, 0);
            acc2[0][n] = __builtin_amdgcn_mfma_f32_16x16x32_bf16(a0, b2, acc2[0][n], 0, 0, 0);
            acc2[1][n] = __builtin_amdgcn_mfma_f32_16x16x32_bf16(a1, b2, acc2[1][n], 0, 0, 0);
        }
    }

    // epilogue: repack via LDS twice (P1 then P2)
#pragma unroll
    for (int pass = 0; pass < 2; ++pass) {
        __syncthreads();
#pragma unroll
        for (int m = 0; m < 2; ++m)
#pragma unroll
            for (int j = 0; j < 4; ++j) {
                int row = wr * 32 + m * 16 + (lane >> 4) * 4 + j;
#pragma unroll
                for (int n = 0; n < 4; ++n) {
                    int c = wc * 64 + n * 16 + (lane & 15);
                    float v = pass == 0 ? acc1[m][n][j] : acc2[m][n][j];
                    As[row * 136 + c] = (__bf16)v;
                }
            }
        __syncthreads();
        if (m_r < M) {
            __bf16* outp = (pass == 0 ? P1 : P2) + (size_t)m_r * C_DIM + q * 32;
#pragma unroll
            for (int i = 0; i < 4; ++i)
                *(bf16x8*)(outp + i * 8) = *(const bf16x8*)&As[r * 136 + q * 32 + i * 8];
        }
    }
}

// ---------------- K4b: xws[e] = (ea[e]@W3 + P1[src]+P2[dst] + b_comb)*dinv  (A streamed!)
__global__ __launch_bounds__(256) void k_gemm3(
    const float* __restrict__ ea, const __bf16* __restrict__ Wf,
    const __bf16* __restrict__ P1, const __bf16* __restrict__ P2,
    const float* __restrict__ b_comb, const int* __restrict__ src,
    const int* __restrict__ dst, const int* __restrict__ indeg,
    __bf16* __restrict__ xws, int E) {

    __shared__ __align__(16) __bf16 As[64 * 136];

    const int tid = threadIdx.x;
    const int ebase = blockIdx.x * 64;
    const int r = tid >> 2, q = tid & 3;
    const int e_r = ebase + r;
    const int e_rc = (e_r < E) ? e_r : 0;
    const float* rp = ea + (size_t)e_rc * C_DIM;

#pragma unroll
    for (int s4 = 0; s4 < 4; ++s4) {
        const float* p = rp + s4 * 32 + q * 8;
        float4 f0 = *(const float4*)p;
        float4 f1 = *(const float4*)(p + 4);
        bf16x8 h;
        h[0] = (__bf16)f0.x; h[1] = (__bf16)f0.y; h[2] = (__bf16)f0.z; h[3] = (__bf16)f0.w;
        h[4] = (__bf16)f1.x; h[5] = (__bf16)f1.y; h[6] = (__bf16)f1.z; h[7] = (__bf16)f1.w;
        int u = s4 * 4 + q;
        *(bf16x8*)&As[r * 128 + ((u ^ (r & 7)) << 3)] = h;
    }
    __syncthreads();

    const int lane = tid & 63, wid = tid >> 6;
    const int wr = wid >> 1, wc = wid & 1;
    const int kc8 = lane >> 4;
    const int arow0 = wr * 32 + (lane & 15);
    const int arow1 = arow0 + 16;
    const __bf16* wfb = Wf + ((size_t)(8 * 8 + wc * 4) * 64 + lane) * 8;   // ks 8..11

    f32x4 acc[2][4] = {};

#pragma unroll
    for (int ks = 0; ks < 4; ++ks) {
        int u = ks * 4 + kc8;
        bf16x8 a0 = *(const bf16x8*)&As[arow0 * 128 + ((u ^ (arow0 & 7)) << 3)];
        bf16x8 a1 = *(const bf16x8*)&As[arow1 * 128 + ((u ^ (arow1 & 7)) << 3)];
#pragma unroll
        for (int n = 0; n < 4; ++n) {
            bf16x8 b = *(const bf16x8*)&wfb[(size_t)(ks * 8 + n) * 64 * 8];
            acc[0][n] = __builtin_amdgcn_mfma_f32_16x16x32_bf16(a0, b, acc[0][n], 0, 0, 0);
            acc[1][n] = __builtin_amdgcn_mfma_f32_16x16x32_bf16(a1, b, acc[1][n], 0, 0, 0);
        }
    }

    // epilogue: raw acc -> LDS bf16, then add gathered P1[src]+P2[dst]+b_comb, *dinv, store
    __syncthreads();
#pragma unroll
    for (int m = 0; m < 2; ++m)
#pragma unroll
        for (int j = 0; j < 4; ++j) {
            int row = wr * 32 + m * 16 + (lane >> 4) * 4 + j;
#pragma unroll
            for (int n = 0; n < 4; ++n) {
                int c = wc * 64 + n * 16 + (lane & 15);
                As[row * 136 + c] = (__bf16)acc[m][n][j];
            }
        }
    __syncthreads();
    if (e_r < E) {
        int s = src[e_r], d = dst[e_r];
        float di = rsqrtf(1.0f + (float)indeg[s]);
        const __bf16* p1 = P1 + (size_t)s * C_DIM + q * 32;
        const __bf16* p2 = P2 + (size_t)d * C_DIM + q * 32;
        const float*  bc = b_comb + q * 32;
        __bf16* outp = xws + (size_t)e_r * C_DIM + q * 32;
#pragma unroll
        for (int i = 0; i < 4; ++i) {
            bf16x8 a8 = *(const bf16x8*)&As[r * 136 + q * 32 + i * 8];
            bf16x8 h1 = *(const bf16x8*)(p1 + i * 8);
            bf16x8 h2 = *(const bf16x8*)(p2 + i * 8);
            float4 b0 = *(const float4*)(bc + i * 8);
            float4 b1 = *(const float4*)(bc + i * 8 + 4);
            bf16x8 o;
#pragma unroll
            for (int j = 0; j < 8; ++j) {
                float bj = j < 4 ? (&b0.x)[j] : (&b1.x)[j - 4];
                float f = ((float)a8[j] + (float)h1[j] + (float)h2[j] + bj) * di;
                o[j] = (__bf16)f;
            }
            *(bf16x8*)(outp + i * 8) = o;
        }
    }
}

// ---------------- K5: agg[v] = sum over incoming edges (CSR gather), 4 nodes/block
__global__ void k_agg(const __bf16* __restrict__ xws, const int* __restrict__ ptr,
                      const int* __restrict__ adj, __bf16* __restrict__ agg, int Nn) {
    int v = blockIdx.x * 4 + (threadIdx.x >> 6);
    if (v >= Nn) return;
    int c = threadIdx.x & 63;           // cols 2c / 2c+1
    int b0 = ptr[v], b1 = ptr[v + 1];
    float s0 = 0.f, s1 = 0.f;
    for (int t = b0; t < b1; ++t) {
        int j = adj[t];
        unsigned u = *(const unsigned*)(xws + (size_t)j * C_DIM + c * 2);
        s0 += bfu_lo(u);
        s1 += bfu_hi(u);
    }
    unsigned o = bf16_bits(s0) | (bf16_bits(s1) << 16);
    *(unsigned*)(agg + (size_t)v * C_DIM + c * 2) = o;
}

// ---------------- K6: out[e] = leaky( dinv[e]*(agg[src[e]] + xws[e]) + b_gcn )
__global__ void k_out(const __bf16* __restrict__ xws, const __bf16* __restrict__ agg,
                      const int* __restrict__ src, const int* __restrict__ indeg,
                      const float* __restrict__ b_gcn, float* __restrict__ out, int E) {
    int g = blockIdx.x * 256 + threadIdx.x;      // one float4-of-output per thread
    if (g >= E * (C_DIM / 4)) return;
    int e = g >> 5, c4 = (g & 31) * 4;
    int s = src[e];
    float di = rsqrtf(1.0f + (float)indeg[s]);
    uint2 u = *(const uint2*)(xws + (size_t)e * C_DIM + c4);
    uint2 au = *(const uint2*)(agg + (size_t)s * C_DIM + c4);
    float4 b = *(const float4*)&b_gcn[c4];
    float4 r;
    r.x = di * (bfu_lo(au.x) + bfu_lo(u.x)) + b.x;
    r.y = di * (bfu_hi(au.x) + bfu_hi(u.x)) + b.y;
    r.z = di * (bfu_lo(au.y) + bfu_lo(u.y)) + b.z;
    r.w = di * (bfu_hi(au.y) + bfu_hi(u.y)) + b.w;
    r.x = r.x > 0.f ? r.x : 0.01f * r.x;
    r.y = r.y > 0.f ? r.y : 0.01f * r.y;
    r.z = r.z > 0.f ? r.z : 0.01f * r.z;
    r.w = r.w > 0.f ? r.w : 0.01f * r.w;
    *(float4*)&out[(size_t)e * C_DIM + c4] = r;
}

extern "C" void kernel_launch(void* const* d_in, const int* in_sizes, int n_in,
                              void* d_out, int out_size, void* d_ws, size_t ws_size,
                              hipStream_t stream) {
    const float* x      = (const float*)d_in[0];
    const float* ea     = (const float*)d_in[1];
    const float* W_edge = (const float*)d_in[2];
    const float* b_edge = (const float*)d_in[3];
    const float* W_gcn  = (const float*)d_in[4];
    const float* b_gcn  = (const float*)d_in[5];
    const int*   ei     = (const int*)d_in[6];
    // d_in[7] = batch (unused), d_in[8] = line_edge_index (unused)

    const int C  = in_sizes[3];            // 128
    const int Nn = in_sizes[0] / C;        // 50000
    const int E  = in_sizes[1] / C;        // 300000
    const int* srcp = ei;
    const int* dstp = ei + E;

    char* ws = (char*)d_ws;
    size_t off = 0;
    auto alloc = [&](size_t bytes) { size_t o = off; off = (off + bytes + 255) & ~(size_t)255; return o; };
    __bf16* Wf     = (__bf16*)(ws + alloc((size_t)384 * 128 * sizeof(__bf16)));
    float*  b_comb = (float*)(ws + alloc(128 * sizeof(float)));
    int*    indeg  = (int*)(ws + alloc((size_t)Nn * sizeof(int)));
    int*    ptr    = (int*)(ws + alloc((size_t)(Nn + 1) * sizeof(int)));
    int*    cursor = (int*)(ws + alloc((size_t)Nn * sizeof(int)));
    int*    adj    = (int*)(ws + alloc((size_t)E * sizeof(int)));
    __bf16* P1     = (__bf16*)(ws + alloc((size_t)Nn * C * sizeof(__bf16)));
    __bf16* P2     = (__bf16*)(ws + alloc((size_t)Nn * C * sizeof(__bf16)));
    __bf16* xws    = (__bf16*)(ws + alloc((size_t)E * C * sizeof(__bf16)));
    __bf16* agg    = (__bf16*)(ws + alloc((size_t)Nn * C * sizeof(__bf16)));

    (void)hipMemsetAsync(indeg, 0, (size_t)Nn * sizeof(int), stream);
    k_wcomb<<<192, 256, 0, stream>>>(W_edge, W_gcn, b_edge, Wf, b_comb);
    k_indeg<<<(E + 255) / 256, 256, 0, stream>>>(dstp, E, indeg);
    k_scan<<<1, 1024, 0, stream>>>(indeg, Nn, ptr, cursor);
    k_place<<<(E + 255) / 256, 256, 0, stream>>>(dstp, E, cursor, adj);
    k_p12<<<(Nn + 63) / 64, 256, 0, stream>>>(x, Wf, P1, P2, Nn);
    k_gemm3<<<(E + 63) / 64, 256, 0, stream>>>(ea, Wf, P1, P2, b_comb, srcp, dstp, indeg, xws, E);
    k_agg<<<(Nn + 3) / 4, 256, 0, stream>>>(xws, ptr, adj, agg, Nn);
    k_out<<<(E * (C / 4) + 255) / 256, 256, 0, stream>>>(xws, agg, srcp, indeg, b_gcn, (float*)d_out, E);
}

// Round 6
// 235.665 us; speedup vs baseline: 1.6908x; 1.2358x over previous
//
#include <hip/hip_runtime.h>
#include <hip/hip_bf16.h>

// Problem: N=50000 nodes, E=300000 edges, C=128.
// Factored: W_comb = W_edge@W_gcn = [W1;W2;W3] (3 x 128x128 blocks).
//   P1 = x@W1 + b_comb, P2 = x@W2      (dense stream GEMMs, bf16)
//   xws[e] = (ea[e]@W3 + P1[src]+P2[dst]) * dinv[e]   (bf16)
//   dinv[e] = rsqrt(1 + indeg(src(e)))
//   agg[v]  = sum_{dst(j)=v} xws[j]  (bf16)
//   out[e]  = leaky( dinv[e]*(agg[src[e]] + xws[e]) + b_gcn )

typedef __bf16 bf16x8 __attribute__((ext_vector_type(8)));
typedef float  f32x4  __attribute__((ext_vector_type(4)));

#define C_DIM 128

__device__ __forceinline__ float bfu_lo(unsigned u) { return __uint_as_float(u << 16); }
__device__ __forceinline__ float bfu_hi(unsigned u) { return __uint_as_float(u & 0xffff0000u); }
__device__ __forceinline__ unsigned bf16_bits(float f) {
    __bf16 h = (__bf16)f;
    return (unsigned)__builtin_bit_cast(unsigned short, h);
}

// ---------------- K0: W_comb in MFMA B-fragment order (12 ks x 8 col16 frags), b_comb
__global__ void k_wcomb(const float* __restrict__ W_edge, const float* __restrict__ W_gcn,
                        const float* __restrict__ b_edge,
                        __bf16* __restrict__ Wf, float* __restrict__ b_comb) {
    int idx = blockIdx.x * 256 + threadIdx.x;        // 384*128 outputs
    if (idx < 384 * 128) {
        int k = idx >> 7, c = idx & 127;
        float s = 0.f;
        for (int m = 0; m < 128; ++m) s += W_edge[k * 128 + m] * W_gcn[m * 128 + c];
        int ks = k >> 5, kc8 = (k >> 3) & 3, j = k & 7;
        int col16 = c >> 4, c15 = c & 15;
        Wf[(size_t)(((ks * 8 + col16) * 64) + kc8 * 16 + c15) * 8 + j] = (__bf16)s;
    }
    if (blockIdx.x == 0 && threadIdx.x < 128) {
        int c = threadIdx.x;
        float s = 0.f;
        for (int m = 0; m < 128; ++m) s += b_edge[m] * W_gcn[m * 128 + c];
        b_comb[c] = s;
    }
}

// ---------------- K1: in-degree (over dst)
__global__ void k_indeg(const int* __restrict__ dst, int E, int* __restrict__ indeg) {
    int e = blockIdx.x * 256 + threadIdx.x;
    if (e < E) atomicAdd(&indeg[dst[e]], 1);
}

// ---------------- K2a: per-block sums of indeg
__global__ void k_scan_bsum(const int* __restrict__ indeg, int n, int* __restrict__ bsum) {
    __shared__ int ws[16];
    int i = blockIdx.x * 1024 + threadIdx.x;
    int v = (i < n) ? indeg[i] : 0;
    int lane = threadIdx.x & 63, wid = threadIdx.x >> 6;
    for (int off = 32; off; off >>= 1) v += __shfl_down(v, off);
    if (lane == 0) ws[wid] = v;
    __syncthreads();
    if (threadIdx.x < 16) {
        int s = ws[threadIdx.x];
        for (int off = 8; off; off >>= 1) s += __shfl_down(s, off);
        if (threadIdx.x == 0) bsum[blockIdx.x] = s;
    }
}

// ---------------- K2b: exclusive scan of block sums (nb <= 64), total -> ptr[n]
__global__ void k_scan_top(int* __restrict__ bsum, int nb, int n, int* __restrict__ ptr) {
    int lane = threadIdx.x;
    int v = (lane < nb) ? bsum[lane] : 0;
    int incl = v;
    for (int off = 1; off < 64; off <<= 1) {
        int t = __shfl_up(incl, off);
        if (lane >= off) incl += t;
    }
    if (lane < nb) bsum[lane] = incl - v;
    if (lane == 63) ptr[n] = incl;
}

// ---------------- K2c: finalize exclusive scan -> ptr, cursor
__global__ void k_scan_fin(const int* __restrict__ indeg, int n, const int* __restrict__ bsum,
                           int* __restrict__ ptr, int* __restrict__ cursor) {
    __shared__ int wsum[16];
    int i = blockIdx.x * 1024 + threadIdx.x;
    int v = (i < n) ? indeg[i] : 0;
    int lane = threadIdx.x & 63, wid = threadIdx.x >> 6;
    int incl = v;
    for (int off = 1; off < 64; off <<= 1) {
        int t = __shfl_up(incl, off);
        if (lane >= off) incl += t;
    }
    if (lane == 63) wsum[wid] = incl;
    __syncthreads();
    if (wid == 0 && lane < 16) {
        int s = wsum[lane];
        for (int off = 1; off < 16; off <<= 1) {
            int t = __shfl_up(s, off);
            if (lane >= off) s += t;
        }
        wsum[lane] = s;
    }
    __syncthreads();
    int woff = wid ? wsum[wid - 1] : 0;
    if (i < n) {
        int ex = bsum[blockIdx.x] + woff + incl - v;
        ptr[i] = ex;
        cursor[i] = ex;
    }
}

// ---------------- K3: place edge ids into CSR-by-dst
__global__ void k_place(const int* __restrict__ dst, int E,
                        int* __restrict__ cursor, int* __restrict__ adj) {
    int e = blockIdx.x * 256 + threadIdx.x;
    if (e < E) {
        int pos = atomicAdd(&cursor[dst[e]], 1);
        adj[pos] = e;
    }
}

// ---------------- K4a: P1 = x@W1 + b_comb, P2 = x@W2
__global__ __launch_bounds__(256) void k_p12(
    const float* __restrict__ x, const __bf16* __restrict__ Wf,
    const float* __restrict__ b_comb,
    __bf16* __restrict__ P1, __bf16* __restrict__ P2, int M) {

    __shared__ __align__(16) __bf16 As[64 * 136];

    const int tid = threadIdx.x;
    const int mbase = blockIdx.x * 64;
    const int r = tid >> 2, q = tid & 3;
    const int m_r = mbase + r;
    const int m_rc = (m_r < M) ? m_r : 0;
    const float* rp = x + (size_t)m_rc * C_DIM;

#pragma unroll
    for (int s4 = 0; s4 < 4; ++s4) {
        const float* p = rp + s4 * 32 + q * 8;
        float4 f0 = *(const float4*)p;
        float4 f1 = *(const float4*)(p + 4);
        bf16x8 h;
        h[0] = (__bf16)f0.x; h[1] = (__bf16)f0.y; h[2] = (__bf16)f0.z; h[3] = (__bf16)f0.w;
        h[4] = (__bf16)f1.x; h[5] = (__bf16)f1.y; h[6] = (__bf16)f1.z; h[7] = (__bf16)f1.w;
        int u = s4 * 4 + q;                              // 16B unit 0..15
        *(bf16x8*)&As[r * 128 + ((u ^ (r & 7)) << 3)] = h;
    }
    __syncthreads();

    const int lane = tid & 63, wid = tid >> 6;
    const int wr = wid >> 1, wc = wid & 1;
    const int kc8 = lane >> 4;
    const int arow0 = wr * 32 + (lane & 15);
    const int arow1 = arow0 + 16;
    const __bf16* wfb = Wf + ((size_t)(wc * 4) * 64 + lane) * 8;

    f32x4 acc1[2][4] = {};
    f32x4 acc2[2][4] = {};

#pragma unroll
    for (int ks = 0; ks < 4; ++ks) {
        int u = ks * 4 + kc8;
        bf16x8 a0 = *(const bf16x8*)&As[arow0 * 128 + ((u ^ (arow0 & 7)) << 3)];
        bf16x8 a1 = *(const bf16x8*)&As[arow1 * 128 + ((u ^ (arow1 & 7)) << 3)];
#pragma unroll
        for (int n = 0; n < 4; ++n) {
            bf16x8 b1 = *(const bf16x8*)&wfb[(size_t)(ks * 8 + n) * 64 * 8];
            bf16x8 b2 = *(const bf16x8*)&wfb[(size_t)((ks + 4) * 8 + n) * 64 * 8];
            acc1[0][n] = __builtin_amdgcn_mfma_f32_16x16x32_bf16(a0, b1, acc1[0][n], 0, 0, 0);
            acc1[1][n] = __builtin_amdgcn_mfma_f32_16x16x32_bf16(a1, b1, acc1[1][n], 0, 0, 0);
            acc2[0][n] = __builtin_amdgcn_mfma_f32_16x16x32_bf16(a0, b2, acc2[0][n], 0, 0, 0);
            acc2[1][n] = __builtin_amdgcn_mfma_f32_16x16x32_bf16(a1, b2, acc2[1][n], 0, 0, 0);
        }
    }

#pragma unroll
    for (int pass = 0; pass < 2; ++pass) {
        __syncthreads();
#pragma unroll
        for (int m = 0; m < 2; ++m)
#pragma unroll
            for (int j = 0; j < 4; ++j) {
                int row = wr * 32 + m * 16 + (lane >> 4) * 4 + j;
#pragma unroll
                for (int n = 0; n < 4; ++n) {
                    int c = wc * 64 + n * 16 + (lane & 15);
                    float v = pass == 0 ? acc1[m][n][j] + b_comb[c] : acc2[m][n][j];
                    As[row * 136 + c] = (__bf16)v;
                }
            }
        __syncthreads();
        if (m_r < M) {
            __bf16* outp = (pass == 0 ? P1 : P2) + (size_t)m_r * C_DIM + q * 32;
#pragma unroll
            for (int i = 0; i < 4; ++i)
                *(bf16x8*)(outp + i * 8) = *(const bf16x8*)&As[r * 136 + q * 32 + i * 8];
        }
    }
}

// ---------------- K4b: xws[e] = (ea[e]@W3 + P1[src]+P2[dst]) * dinv
// Gathers issued BEFORE the first barrier so their latency overlaps the ea staging.
__global__ __launch_bounds__(256) void k_gemm3(
    const float* __restrict__ ea, const __bf16* __restrict__ Wf,
    const __bf16* __restrict__ P1, const __bf16* __restrict__ P2,
    const int* __restrict__ src, const int* __restrict__ dst,
    const int* __restrict__ indeg, __bf16* __restrict__ xws, int E) {

    __shared__ __align__(16) __bf16 As[64 * 136];

    const int tid = threadIdx.x;
    const int ebase = blockIdx.x * 64;
    const int r = tid >> 2, q = tid & 3;
    const int e_r = ebase + r;
    const int e_rc = (e_r < E) ? e_r : 0;
    const float* rp = ea + (size_t)e_rc * C_DIM;

    // early epilogue loads: src/dst -> P1/P2 row chunks into regs
    const int s_e = src[e_rc], d_e = dst[e_rc];
    const float di = rsqrtf(1.0f + (float)indeg[s_e]);
    uint4 g1[4], g2[4];
    {
        const uint4* p1 = (const uint4*)(P1 + (size_t)s_e * C_DIM + q * 32);
        const uint4* p2 = (const uint4*)(P2 + (size_t)d_e * C_DIM + q * 32);
#pragma unroll
        for (int i = 0; i < 4; ++i) { g1[i] = p1[i]; g2[i] = p2[i]; }
    }

#pragma unroll
    for (int s4 = 0; s4 < 4; ++s4) {
        const float* p = rp + s4 * 32 + q * 8;
        float4 f0 = *(const float4*)p;
        float4 f1 = *(const float4*)(p + 4);
        bf16x8 h;
        h[0] = (__bf16)f0.x; h[1] = (__bf16)f0.y; h[2] = (__bf16)f0.z; h[3] = (__bf16)f0.w;
        h[4] = (__bf16)f1.x; h[5] = (__bf16)f1.y; h[6] = (__bf16)f1.z; h[7] = (__bf16)f1.w;
        int u = s4 * 4 + q;
        *(bf16x8*)&As[r * 128 + ((u ^ (r & 7)) << 3)] = h;
    }
    __syncthreads();

    const int lane = tid & 63, wid = tid >> 6;
    const int wr = wid >> 1, wc = wid & 1;
    const int kc8 = lane >> 4;
    const int arow0 = wr * 32 + (lane & 15);
    const int arow1 = arow0 + 16;
    const __bf16* wfb = Wf + ((size_t)(8 * 8 + wc * 4) * 64 + lane) * 8;   // ks 8..11

    f32x4 acc[2][4] = {};

#pragma unroll
    for (int ks = 0; ks < 4; ++ks) {
        int u = ks * 4 + kc8;
        bf16x8 a0 = *(const bf16x8*)&As[arow0 * 128 + ((u ^ (arow0 & 7)) << 3)];
        bf16x8 a1 = *(const bf16x8*)&As[arow1 * 128 + ((u ^ (arow1 & 7)) << 3)];
#pragma unroll
        for (int n = 0; n < 4; ++n) {
            bf16x8 b = *(const bf16x8*)&wfb[(size_t)(ks * 8 + n) * 64 * 8];
            acc[0][n] = __builtin_amdgcn_mfma_f32_16x16x32_bf16(a0, b, acc[0][n], 0, 0, 0);
            acc[1][n] = __builtin_amdgcn_mfma_f32_16x16x32_bf16(a1, b, acc[1][n], 0, 0, 0);
        }
    }

    // repack acc via LDS, then combine with register-held gathers and store
    __syncthreads();
#pragma unroll
    for (int m = 0; m < 2; ++m)
#pragma unroll
        for (int j = 0; j < 4; ++j) {
            int row = wr * 32 + m * 16 + (lane >> 4) * 4 + j;
#pragma unroll
            for (int n = 0; n < 4; ++n) {
                int c = wc * 64 + n * 16 + (lane & 15);
                As[row * 136 + c] = (__bf16)acc[m][n][j];
            }
        }
    __syncthreads();
    if (e_r < E) {
        __bf16* outp = xws + (size_t)e_r * C_DIM + q * 32;
#pragma unroll
        for (int i = 0; i < 4; ++i) {
            bf16x8 a8 = *(const bf16x8*)&As[r * 136 + q * 32 + i * 8];
            bf16x8 h1 = __builtin_bit_cast(bf16x8, g1[i]);
            bf16x8 h2 = __builtin_bit_cast(bf16x8, g2[i]);
            bf16x8 o;
#pragma unroll
            for (int j = 0; j < 8; ++j)
                o[j] = (__bf16)(((float)a8[j] + (float)h1[j] + (float)h2[j]) * di);
            *(bf16x8*)(outp + i * 8) = o;
        }
    }
}

// ---------------- K5: agg[v] = sum over incoming edges (CSR gather), 4 nodes/block
__global__ void k_agg(const __bf16* __restrict__ xws, const int* __restrict__ ptr,
                      const int* __restrict__ adj, __bf16* __restrict__ agg, int Nn) {
    int v = blockIdx.x * 4 + (threadIdx.x >> 6);
    if (v >= Nn) return;
    int c = threadIdx.x & 63;           // cols 2c / 2c+1
    int b0 = ptr[v], b1 = ptr[v + 1];
    float s0 = 0.f, s1 = 0.f;
    for (int t = b0; t < b1; ++t) {
        int j = adj[t];
        unsigned u = *(const unsigned*)(xws + (size_t)j * C_DIM + c * 2);
        s0 += bfu_lo(u);
        s1 += bfu_hi(u);
    }
    unsigned o = bf16_bits(s0) | (bf16_bits(s1) << 16);
    *(unsigned*)(agg + (size_t)v * C_DIM + c * 2) = o;
}

// ---------------- K6: out[e] = leaky( dinv[e]*(agg[src[e]] + xws[e]) + b_gcn )
__global__ void k_out(const __bf16* __restrict__ xws, const __bf16* __restrict__ agg,
                      const int* __restrict__ src, const int* __restrict__ indeg,
                      const float* __restrict__ b_gcn, float* __restrict__ out, int E) {
    int g = blockIdx.x * 256 + threadIdx.x;      // one float4-of-output per thread
    if (g >= E * (C_DIM / 4)) return;
    int e = g >> 5, c4 = (g & 31) * 4;
    int s = src[e];
    float di = rsqrtf(1.0f + (float)indeg[s]);
    uint2 u = *(const uint2*)(xws + (size_t)e * C_DIM + c4);
    uint2 au = *(const uint2*)(agg + (size_t)s * C_DIM + c4);
    float4 b = *(const float4*)&b_gcn[c4];
    float4 r;
    r.x = di * (bfu_lo(au.x) + bfu_lo(u.x)) + b.x;
    r.y = di * (bfu_hi(au.x) + bfu_hi(u.x)) + b.y;
    r.z = di * (bfu_lo(au.y) + bfu_lo(u.y)) + b.z;
    r.w = di * (bfu_hi(au.y) + bfu_hi(u.y)) + b.w;
    r.x = r.x > 0.f ? r.x : 0.01f * r.x;
    r.y = r.y > 0.f ? r.y : 0.01f * r.y;
    r.z = r.z > 0.f ? r.z : 0.01f * r.z;
    r.w = r.w > 0.f ? r.w : 0.01f * r.w;
    *(float4*)&out[(size_t)e * C_DIM + c4] = r;
}

extern "C" void kernel_launch(void* const* d_in, const int* in_sizes, int n_in,
                              void* d_out, int out_size, void* d_ws, size_t ws_size,
                              hipStream_t stream) {
    const float* x      = (const float*)d_in[0];
    const float* ea     = (const float*)d_in[1];
    const float* W_edge = (const float*)d_in[2];
    const float* b_edge = (const float*)d_in[3];
    const float* W_gcn  = (const float*)d_in[4];
    const float* b_gcn  = (const float*)d_in[5];
    const int*   ei     = (const int*)d_in[6];
    // d_in[7] = batch (unused), d_in[8] = line_edge_index (unused)

    const int C  = in_sizes[3];            // 128
    const int Nn = in_sizes[0] / C;        // 50000
    const int E  = in_sizes[1] / C;        // 300000
    const int* srcp = ei;
    const int* dstp = ei + E;

    char* ws = (char*)d_ws;
    size_t off = 0;
    auto alloc = [&](size_t bytes) { size_t o = off; off = (off + bytes + 255) & ~(size_t)255; return o; };
    __bf16* Wf     = (__bf16*)(ws + alloc((size_t)384 * 128 * sizeof(__bf16)));
    float*  b_comb = (float*)(ws + alloc(128 * sizeof(float)));
    int*    indeg  = (int*)(ws + alloc((size_t)Nn * sizeof(int)));
    int*    ptr    = (int*)(ws + alloc((size_t)(Nn + 1) * sizeof(int)));
    int*    cursor = (int*)(ws + alloc((size_t)Nn * sizeof(int)));
    int*    bsum   = (int*)(ws + alloc(64 * sizeof(int)));
    int*    adj    = (int*)(ws + alloc((size_t)E * sizeof(int)));
    __bf16* P1     = (__bf16*)(ws + alloc((size_t)Nn * C * sizeof(__bf16)));
    __bf16* P2     = (__bf16*)(ws + alloc((size_t)Nn * C * sizeof(__bf16)));
    __bf16* xws    = (__bf16*)(ws + alloc((size_t)E * C * sizeof(__bf16)));
    __bf16* agg    = (__bf16*)(ws + alloc((size_t)Nn * C * sizeof(__bf16)));

    const int nb = (Nn + 1023) / 1024;     // 49

    (void)hipMemsetAsync(indeg, 0, (size_t)Nn * sizeof(int), stream);
    k_wcomb<<<192, 256, 0, stream>>>(W_edge, W_gcn, b_edge, Wf, b_comb);
    k_indeg<<<(E + 255) / 256, 256, 0, stream>>>(dstp, E, indeg);
    k_scan_bsum<<<nb, 1024, 0, stream>>>(indeg, Nn, bsum);
    k_scan_top<<<1, 64, 0, stream>>>(bsum, nb, Nn, ptr);
    k_scan_fin<<<nb, 1024, 0, stream>>>(indeg, Nn, bsum, ptr, cursor);
    k_place<<<(E + 255) / 256, 256, 0, stream>>>(dstp, E, cursor, adj);
    k_p12<<<(Nn + 63) / 64, 256, 0, stream>>>(x, Wf, b_comb, P1, P2, Nn);
    k_gemm3<<<(E + 63) / 64, 256, 0, stream>>>(ea, Wf, P1, P2, srcp, dstp, indeg, xws, E);
    k_agg<<<(Nn + 3) / 4, 256, 0, stream>>>(xws, ptr, adj, agg, Nn);
    k_out<<<(E * (C / 4) + 255) / 256, 256, 0, stream>>>(xws, agg, srcp, indeg, b_gcn, (float*)d_out, E);
}